// Round 2
// baseline (146.410 us; speedup 1.0000x reference)
//
#include <hip/hip_runtime.h>
#include <math.h>

#define BB 4
#define NN 8192
#define KNB 16
#define DD 128
#define SS 17            // K+1 (self + neighbors)
#define M_TOT (BB*NN)    // 32768
#define WPAD 136         // padded inner stride (elems) for LDS tiles

typedef __attribute__((ext_vector_type(8))) short          bf8;
typedef __attribute__((ext_vector_type(4))) float          f4;
typedef __attribute__((ext_vector_type(4))) unsigned short u16x4;

static __device__ __forceinline__ unsigned short f2bf(float f) {
    unsigned u = __builtin_bit_cast(unsigned, f);
    u += 0x7fffu + ((u >> 16) & 1u);        // round-to-nearest-even
    return (unsigned short)(u >> 16);
}
static __device__ __forceinline__ float bf2f_s(short h) {
    return __builtin_bit_cast(float, (unsigned)(unsigned short)h << 16);
}

// ---------------------------------------------------------------------------
// Transpose+convert the six 128x128 fp32 weights to bf16 W^T[n][k].
// (round-0 proven version; X stays fp32 and is converted during qkv staging)
// ---------------------------------------------------------------------------
__global__ __launch_bounds__(256) void cvt_wT(
    const float* __restrict__ Wq, const float* __restrict__ Wk,
    const float* __restrict__ Wv, const float* __restrict__ Wo,
    const float* __restrict__ W1, const float* __restrict__ W2,
    unsigned short* __restrict__ out)
{
    int m = blockIdx.x >> 4;
    const float* src = (m == 0) ? Wq : (m == 1) ? Wk : (m == 2) ? Wv
                     : (m == 3) ? Wo : (m == 4) ? W1 : W2;
    unsigned short* dst = out + m * 16384;
    int o = (blockIdx.x & 15) * 1024 + threadIdx.x * 4;   // output idx [n][k]
    int n = o >> 7, k = o & 127;
    u16x4 r;
    #pragma unroll
    for (int i = 0; i < 4; ++i) r[i] = f2bf(src[(size_t)(k + i) * 128 + n]);
    *(u16x4*)(dst + o) = r;
}

// ---------------------------------------------------------------------------
// Fused fp32->bf16 convert + QKV projection (round-0 proven structure).
// 64 rows/block, 4 waves; X staged ONCE, afr persistent across 3 GEMMs.
// Fragment maps (m89-verified): A[m=lane&15][k=quad*8+j],
// B[k=quad*8+j][n=lane&15], D[row=quad*4+r][col=lane&15].
// LDS 17.4 + 34.8 = 52.2 KB -> 3 blocks/CU.
// ---------------------------------------------------------------------------
__global__ __launch_bounds__(256) void qkv_kernel(
    const float* __restrict__ X, const unsigned short* __restrict__ WtT,
    const float* __restrict__ bq, const float* __restrict__ bk,
    const float* __restrict__ bv,
    unsigned short* __restrict__ qh, unsigned short* __restrict__ kh,
    unsigned short* __restrict__ vh)
{
    __shared__ unsigned short Xs[64 * WPAD];    // 17408 B
    __shared__ unsigned short Wb[128 * WPAD];   // 34816 B

    const int tid  = threadIdx.x;
    const int row0 = blockIdx.x * 64;

    // Stage X tile fp32 -> bf16 (coalesced float4 reads)
    {
        const float4* Xg = (const float4*)(X + (size_t)row0 * DD);
        #pragma unroll
        for (int i = 0; i < 8; ++i) {
            int idx = tid + i * 256;            // 0..2047
            int r = idx >> 5, c4 = idx & 31;
            float4 v = Xg[idx];
            u16x4 u;
            u[0] = f2bf(v.x); u[1] = f2bf(v.y); u[2] = f2bf(v.z); u[3] = f2bf(v.w);
            *(u16x4*)(Xs + r * WPAD + c4 * 4) = u;
        }
    }
    // Stage Wq^T
    #pragma unroll
    for (int i = 0; i < 8; ++i) {
        int c = tid + i * 256;
        int n = c >> 4, k8 = c & 15;
        *(bf8*)(Wb + n * WPAD + k8 * 8) = ((const bf8*)WtT)[c];
    }

    const int lane = tid & 63, wv = tid >> 6;   // wave owns rows wv*16..+15
    const int ln = lane & 15, quad = lane >> 4;
    __syncthreads();

    // A-frags: persistent across the 3 GEMMs (4 k-steps, 16 regs)
    bf8 afr[4];
    #pragma unroll
    for (int s = 0; s < 4; ++s)
        afr[s] = *(const bf8*)(Xs + (wv * 16 + ln) * WPAD + s * 32 + quad * 8);

    const float* biases[3] = { bq, bk, bv };
    unsigned short* outs[3] = { qh, kh, vh };

    #pragma unroll 1
    for (int g = 0; g < 3; ++g) {
        if (g > 0) {
            __syncthreads();   // all waves done reading Wb for g-1
            const bf8* Wn = (const bf8*)(WtT + g * 16384);
            #pragma unroll
            for (int i = 0; i < 8; ++i) {
                int c = tid + i * 256;
                int n = c >> 4, k8 = c & 15;
                *(bf8*)(Wb + n * WPAD + k8 * 8) = Wn[c];
            }
            __syncthreads();
        }

        f4 acc[8] = {};
        #pragma unroll
        for (int t = 0; t < 8; ++t) {
            bf8 bfr[4];
            #pragma unroll
            for (int s = 0; s < 4; ++s)
                bfr[s] = *(const bf8*)(Wb + (t * 16 + ln) * WPAD + s * 32 + quad * 8);
            #pragma unroll
            for (int s = 0; s < 4; ++s)
                acc[t] = __builtin_amdgcn_mfma_f32_16x16x32_bf16(afr[s], bfr[s], acc[t], 0, 0, 0);
        }

        const float* bias = biases[g];
        unsigned short* Y = outs[g];
        #pragma unroll
        for (int t = 0; t < 8; ++t) {
            int col = t * 16 + ln;
            float bc = bias[col];
            #pragma unroll
            for (int r = 0; r < 4; ++r) {
                int row = row0 + wv * 16 + quad * 4 + r;
                Y[(size_t)row * DD + col] = f2bf(acc[t][r] + bc);
            }
        }
    }
}

// ---------------------------------------------------------------------------
// FUSED attention + Wo/FFN. Block = 64 vertices (= one ffn row tile), 256 thr.
// Attn geometry: 4 lanes per vertex, lane = head (DK=32): the q.k dot is
// fully in-lane -> ZERO shuffles (round-0 needed 2 shfl_xor per score).
// Loads UNGUARDED (gather is L2-latency-bound; guards serialize the load
// pipeline — round-1 lesson); masking is arithmetic: sc=-1e9 -> exp()=0.
// ctx goes straight to LDS Ct (never to global), then the proven 3-GEMM
// ffn chain (Wo -> relu(W1) -> W2) runs from it. Wo staging is issued
// BEFORE the attn phase so its latency hides under the gather.
// LDS 17.4 + 34.8 = 52.2 KB -> 3 blocks/CU.
// ---------------------------------------------------------------------------
__global__ __launch_bounds__(256) void attn_ffn_kernel(
    const unsigned short* __restrict__ Qh, const unsigned short* __restrict__ Kh,
    const unsigned short* __restrict__ Vh, const int* __restrict__ nbr,
    const int* __restrict__ vlen, const unsigned short* __restrict__ WtT3,
    const float* __restrict__ bo, const float* __restrict__ b1,
    const float* __restrict__ b2, float* __restrict__ Out)
{
    __shared__ unsigned short Ct[64 * WPAD];    // ctx tile (attn output)
    __shared__ unsigned short Wb[128 * WPAD];

    const int tid  = threadIdx.x;
    const int row0 = blockIdx.x * 64;

    // Issue Wo^T staging now; completes under the attn phase (barrier below
    // implies vmcnt(0) before any wave proceeds to the ffn GEMM).
    #pragma unroll
    for (int i = 0; i < 8; ++i) {
        int c = tid + i * 256;
        int n = c >> 4, k8 = c & 15;
        *(bf8*)(Wb + n * WPAD + k8 * 8) = ((const bf8*)WtT3)[c];
    }

    // ---------------- attention (4 lanes/vertex, in-lane head dot) --------
    const int vloc = tid >> 2;        // 0..63
    const int h    = tid & 3;         // head
    const int v    = row0 + vloc;
    const int b    = v >> 13;         // v / NN
    const int len  = vlen[v];         // rows 0..len valid (len in [0,16))

    // q fragment: this head's 32 dims, as floats
    float qf[32];
    {
        const bf8* qp = (const bf8*)(Qh + (size_t)v * DD + h * 32);
        #pragma unroll
        for (int j = 0; j < 4; ++j) {
            bf8 q8 = qp[j];
            #pragma unroll
            for (int i = 0; i < 8; ++i) qf[j * 8 + i] = bf2f_s(q8[i]);
        }
    }

    int rows[SS];
    rows[0] = v;
    {
        const int4* np = (const int4*)(nbr + (size_t)v * KNB);
        #pragma unroll
        for (int i = 0; i < 4; ++i) {
            int4 n4 = np[i];
            rows[1 + i * 4 + 0] = (b << 13) + n4.x;
            rows[1 + i * 4 + 1] = (b << 13) + n4.y;
            rows[1 + i * 4 + 2] = (b << 13) + n4.z;
            rows[1 + i * 4 + 3] = (b << 13) + n4.w;
        }
    }

    // Pass 1: scores. Unguarded loads, arithmetic mask.
    float sc[SS];
    #pragma unroll
    for (int s = 0; s < SS; ++s) {
        const bf8* kp = (const bf8*)(Kh + (size_t)rows[s] * DD + h * 32);
        bf8 k0 = kp[0], k1 = kp[1], k2 = kp[2], k3 = kp[3];
        float p = 0.f;
        #pragma unroll
        for (int i = 0; i < 8; ++i) p = fmaf(qf[i],      bf2f_s(k0[i]), p);
        #pragma unroll
        for (int i = 0; i < 8; ++i) p = fmaf(qf[8 + i],  bf2f_s(k1[i]), p);
        #pragma unroll
        for (int i = 0; i < 8; ++i) p = fmaf(qf[16 + i], bf2f_s(k2[i]), p);
        #pragma unroll
        for (int i = 0; i < 8; ++i) p = fmaf(qf[24 + i], bf2f_s(k3[i]), p);
        sc[s] = (s <= len) ? p * 0.17677669529663687f : -1.0e9f;  // 1/sqrt(32)
    }

    // Softmax (per lane = per head), unguarded: exp(-1e9 - m) == 0.
    float m = sc[0];
    #pragma unroll
    for (int s = 1; s < SS; ++s) m = fmaxf(m, sc[s]);
    float sum = 0.f;
    #pragma unroll
    for (int s = 0; s < SS; ++s) {
        float e = __expf(sc[s] - m);
        sc[s] = e;
        sum += e;
    }
    const float inv = 1.f / sum;

    // Pass 2: weighted V accumulate (invalid rows contribute w == 0).
    float acc[32] = {};
    #pragma unroll
    for (int s = 0; s < SS; ++s) {
        const bf8* vp = (const bf8*)(Vh + (size_t)rows[s] * DD + h * 32);
        bf8 v0 = vp[0], v1 = vp[1], v2 = vp[2], v3 = vp[3];
        float w = sc[s] * inv;
        #pragma unroll
        for (int i = 0; i < 8; ++i) acc[i]      = fmaf(w, bf2f_s(v0[i]), acc[i]);
        #pragma unroll
        for (int i = 0; i < 8; ++i) acc[8 + i]  = fmaf(w, bf2f_s(v1[i]), acc[8 + i]);
        #pragma unroll
        for (int i = 0; i < 8; ++i) acc[16 + i] = fmaf(w, bf2f_s(v2[i]), acc[16 + i]);
        #pragma unroll
        for (int i = 0; i < 8; ++i) acc[24 + i] = fmaf(w, bf2f_s(v3[i]), acc[24 + i]);
    }

    // ctx -> LDS (bf16), layout [vloc][h*32 + k] = (H,DK) flattened = Wo input
    #pragma unroll
    for (int j = 0; j < 4; ++j) {
        bf8 r;
        #pragma unroll
        for (int i = 0; i < 8; ++i) r[i] = (short)f2bf(acc[j * 8 + i]);
        *(bf8*)(Ct + vloc * WPAD + h * 32 + j * 8) = r;
    }

    __syncthreads();    // Ct complete + Wb(Wo) staging complete

    // ---------------- Wo -> relu(W1) -> W2 chain (proven ffn structure) ---
    const int lane = tid & 63, wv = tid >> 6;
    const int ln = lane & 15, quad = lane >> 4;
    const float* biases[3] = { bo, b1, b2 };

    #pragma unroll 1
    for (int g = 0; g < 3; ++g) {
        bf8 afr[4];
        #pragma unroll
        for (int s = 0; s < 4; ++s)
            afr[s] = *(const bf8*)(Ct + (wv * 16 + ln) * WPAD + s * 32 + quad * 8);

        f4 facc[8] = {};
        #pragma unroll
        for (int t = 0; t < 8; ++t) {
            bf8 bfr[4];
            #pragma unroll
            for (int s = 0; s < 4; ++s)
                bfr[s] = *(const bf8*)(Wb + (t * 16 + ln) * WPAD + s * 32 + quad * 8);
            #pragma unroll
            for (int s = 0; s < 4; ++s)
                facc[t] = __builtin_amdgcn_mfma_f32_16x16x32_bf16(afr[s], bfr[s], facc[t], 0, 0, 0);
        }

        __syncthreads();   // everyone done reading Ct & Wb

        const float* bias = biases[g];
        if (g == 2) {
            #pragma unroll
            for (int t = 0; t < 8; ++t) {
                int col = t * 16 + ln;
                float bc = bias[col];
                #pragma unroll
                for (int r = 0; r < 4; ++r) {
                    int row = row0 + wv * 16 + quad * 4 + r;
                    Out[(size_t)row * DD + col] = facc[t][r] + bc;
                }
            }
        } else {
            // stage next W while Ct is being rewritten
            const bf8* Wn = (const bf8*)(WtT3 + (g + 1) * 16384);
            #pragma unroll
            for (int i = 0; i < 8; ++i) {
                int c = tid + i * 256;
                int n = c >> 4, k8 = c & 15;
                *(bf8*)(Wb + n * WPAD + k8 * 8) = Wn[c];
            }
            #pragma unroll
            for (int t = 0; t < 8; ++t) {
                int col = t * 16 + ln;
                float bc = bias[col];
                #pragma unroll
                for (int r = 0; r < 4; ++r) {
                    int rloc = wv * 16 + quad * 4 + r;
                    float vv = facc[t][r] + bc;
                    if (g == 1) vv = fmaxf(vv, 0.f);
                    Ct[rloc * WPAD + col] = f2bf(vv);
                }
            }
            __syncthreads();   // new Ct + Wb visible before next g
        }
    }
}

// ---------------------------------------------------------------------------
extern "C" void kernel_launch(void* const* d_in, const int* in_sizes, int n_in,
                              void* d_out, int out_size, void* d_ws, size_t ws_size,
                              hipStream_t stream)
{
    const float* vf   = (const float*)d_in[0];
    const int*   nbr  = (const int*)  d_in[1];
    const int*   vlen = (const int*)  d_in[2];
    const float* Wq   = (const float*)d_in[3];
    const float* bq   = (const float*)d_in[4];
    const float* Wk   = (const float*)d_in[5];
    const float* bk   = (const float*)d_in[6];
    const float* Wv   = (const float*)d_in[7];
    const float* bv   = (const float*)d_in[8];
    const float* Wo   = (const float*)d_in[9];
    const float* bo   = (const float*)d_in[10];
    const float* W1   = (const float*)d_in[11];
    const float* b1   = (const float*)d_in[12];
    const float* W2   = (const float*)d_in[13];
    const float* b2   = (const float*)d_in[14];

    float* out = (float*)d_out;

    const size_t SZ = (size_t)M_TOT * DD;
    unsigned short* WtT = (unsigned short*)d_ws;    // 6 x 16384 bf16
    unsigned short* qh  = WtT + 6 * 16384;
    unsigned short* kh  = qh + SZ;
    unsigned short* vh  = kh + SZ;

    cvt_wT<<<96, 256, 0, stream>>>(Wq, Wk, Wv, Wo, W1, W2, WtT);

    qkv_kernel<<<M_TOT / 64, 256, 0, stream>>>(vf, WtT, bq, bk, bv, qh, kh, vh);

    attn_ffn_kernel<<<M_TOT / 64, 256, 0, stream>>>(qh, kh, vh, nbr, vlen,
                                                    WtT + 3 * 16384, bo, b1, b2, out);
}

// Round 3
// 143.731 us; speedup vs baseline: 1.0186x; 1.0186x over previous
//
#include <hip/hip_runtime.h>
#include <math.h>

#define BB 4
#define NN 8192
#define KNB 16
#define DD 128
#define SS 17            // K+1 (self + neighbors)
#define M_TOT (BB*NN)    // 32768
#define WPAD 136         // padded inner stride (elems) for LDS tiles

typedef __attribute__((ext_vector_type(8))) short          bf8;
typedef __attribute__((ext_vector_type(4))) float          f4;
typedef __attribute__((ext_vector_type(4))) unsigned short u16x4;

static __device__ __forceinline__ unsigned short f2bf(float f) {
    unsigned u = __builtin_bit_cast(unsigned, f);
    u += 0x7fffu + ((u >> 16) & 1u);        // round-to-nearest-even
    return (unsigned short)(u >> 16);
}
static __device__ __forceinline__ float bf2f_s(short h) {
    return __builtin_bit_cast(float, (unsigned)(unsigned short)h << 16);
}

// ---------------------------------------------------------------------------
// Transpose+convert the six 128x128 fp32 weights to bf16 W^T[n][k].
// ---------------------------------------------------------------------------
__global__ __launch_bounds__(256) void cvt_wT(
    const float* __restrict__ Wq, const float* __restrict__ Wk,
    const float* __restrict__ Wv, const float* __restrict__ Wo,
    const float* __restrict__ W1, const float* __restrict__ W2,
    unsigned short* __restrict__ out)
{
    int m = blockIdx.x >> 4;
    const float* src = (m == 0) ? Wq : (m == 1) ? Wk : (m == 2) ? Wv
                     : (m == 3) ? Wo : (m == 4) ? W1 : W2;
    unsigned short* dst = out + m * 16384;
    int o = (blockIdx.x & 15) * 1024 + threadIdx.x * 4;   // output idx [n][k]
    int n = o >> 7, k = o & 127;
    u16x4 r;
    #pragma unroll
    for (int i = 0; i < 4; ++i) r[i] = f2bf(src[(size_t)(k + i) * 128 + n]);
    *(u16x4*)(dst + o) = r;
}

// ---------------------------------------------------------------------------
// Fused fp32->bf16 convert + QKV projection (round-0 proven structure).
// 64 rows/block, 4 waves; X staged ONCE, afr persistent across 3 GEMMs.
// Fragment maps (m89-verified): A[m=lane&15][k=quad*8+j],
// B[k=quad*8+j][n=lane&15], D[row=quad*4+r][col=lane&15].
// LDS 17.4 + 34.8 = 52.2 KB -> 3 blocks/CU. Here Wb staging DOES pay:
// each weight element is reused 4x (64 rows / 16-row tile).
// ---------------------------------------------------------------------------
__global__ __launch_bounds__(256) void qkv_kernel(
    const float* __restrict__ X, const unsigned short* __restrict__ WtT,
    const float* __restrict__ bq, const float* __restrict__ bk,
    const float* __restrict__ bv,
    unsigned short* __restrict__ qh, unsigned short* __restrict__ kh,
    unsigned short* __restrict__ vh)
{
    __shared__ unsigned short Xs[64 * WPAD];    // 17408 B
    __shared__ unsigned short Wb[128 * WPAD];   // 34816 B

    const int tid  = threadIdx.x;
    const int row0 = blockIdx.x * 64;

    // Stage X tile fp32 -> bf16 (coalesced float4 reads)
    {
        const float4* Xg = (const float4*)(X + (size_t)row0 * DD);
        #pragma unroll
        for (int i = 0; i < 8; ++i) {
            int idx = tid + i * 256;            // 0..2047
            int r = idx >> 5, c4 = idx & 31;
            float4 v = Xg[idx];
            u16x4 u;
            u[0] = f2bf(v.x); u[1] = f2bf(v.y); u[2] = f2bf(v.z); u[3] = f2bf(v.w);
            *(u16x4*)(Xs + r * WPAD + c4 * 4) = u;
        }
    }
    // Stage Wq^T
    #pragma unroll
    for (int i = 0; i < 8; ++i) {
        int c = tid + i * 256;
        int n = c >> 4, k8 = c & 15;
        *(bf8*)(Wb + n * WPAD + k8 * 8) = ((const bf8*)WtT)[c];
    }

    const int lane = tid & 63, wv = tid >> 6;   // wave owns rows wv*16..+15
    const int ln = lane & 15, quad = lane >> 4;
    __syncthreads();

    // A-frags: persistent across the 3 GEMMs (4 k-steps, 16 regs)
    bf8 afr[4];
    #pragma unroll
    for (int s = 0; s < 4; ++s)
        afr[s] = *(const bf8*)(Xs + (wv * 16 + ln) * WPAD + s * 32 + quad * 8);

    const float* biases[3] = { bq, bk, bv };
    unsigned short* outs[3] = { qh, kh, vh };

    #pragma unroll 1
    for (int g = 0; g < 3; ++g) {
        if (g > 0) {
            __syncthreads();   // all waves done reading Wb for g-1
            const bf8* Wn = (const bf8*)(WtT + g * 16384);
            #pragma unroll
            for (int i = 0; i < 8; ++i) {
                int c = tid + i * 256;
                int n = c >> 4, k8 = c & 15;
                *(bf8*)(Wb + n * WPAD + k8 * 8) = Wn[c];
            }
            __syncthreads();
        }

        f4 acc[8] = {};
        #pragma unroll
        for (int t = 0; t < 8; ++t) {
            bf8 bfr[4];
            #pragma unroll
            for (int s = 0; s < 4; ++s)
                bfr[s] = *(const bf8*)(Wb + (t * 16 + ln) * WPAD + s * 32 + quad * 8);
            #pragma unroll
            for (int s = 0; s < 4; ++s)
                acc[t] = __builtin_amdgcn_mfma_f32_16x16x32_bf16(afr[s], bfr[s], acc[t], 0, 0, 0);
        }

        const float* bias = biases[g];
        unsigned short* Y = outs[g];
        #pragma unroll
        for (int t = 0; t < 8; ++t) {
            int col = t * 16 + ln;
            float bc = bias[col];
            #pragma unroll
            for (int r = 0; r < 4; ++r) {
                int row = row0 + wv * 16 + quad * 4 + r;
                Y[(size_t)row * DD + col] = f2bf(acc[t][r] + bc);
            }
        }
    }
}

// ---------------------------------------------------------------------------
// FUSED attention + Wo/FFN at ATTENTION-friendly granularity.
// Block = 16 vertices, 256 threads, grid 2048 (round-0's proven attn
// geometry: 16 lanes/vertex, lane owns 8 dims, head = 4 lanes, 2 shfl_xor).
// ctx -> 4.4 KB LDS tile only (never global). FFN chain reads A-frags from
// LDS; B-frags are read DIRECTLY from L2-hot weights — at 16 rows/block a
// weight element feeds exactly one 16x16 tile, so LDS staging has zero
// reuse and is pure overhead (round-2 lesson: the 52 KB Wb tile +
// 512-block grid collapsed occupancy to 9.4%).
// __launch_bounds__(256,4): VGPR<=128 -> 16 waves/CU, 4 blocks/CU.
// ---------------------------------------------------------------------------
__global__ __launch_bounds__(256, 4) void attn_ffn_kernel(
    const unsigned short* __restrict__ Qh, const unsigned short* __restrict__ Kh,
    const unsigned short* __restrict__ Vh, const int* __restrict__ nbr,
    const int* __restrict__ vlen, const unsigned short* __restrict__ WtT3,
    const float* __restrict__ bo, const float* __restrict__ b1,
    const float* __restrict__ b2, float* __restrict__ Out)
{
    __shared__ unsigned short Ct[16 * WPAD];    // 4352 B — the only LDS

    const int tid  = threadIdx.x;
    const int vloc = tid >> 4;        // 0..15
    const int ln16 = tid & 15;        // 8-dim slot
    const int blk  = blockIdx.x;
    const int b    = (blk & 7) >> 1;                 // batch from XCD pair
    const int j    = ((blk >> 3) << 1) | (blk & 1);  // within-batch group 0..511
    const int row0 = b * NN + j * 16;
    const int v    = row0 + vloc;

    // ---------------- attention (round-0 proven body) ---------------------
    bf8 q8 = *(const bf8*)(Qh + (size_t)v * DD + ln16 * 8);
    float qf[8];
    #pragma unroll
    for (int i = 0; i < 8; ++i) qf[i] = bf2f_s(q8[i]);

    int rows[SS];
    rows[0] = v;
    {
        const int4* np = (const int4*)(nbr + (size_t)v * KNB);
        #pragma unroll
        for (int i = 0; i < 4; ++i) {
            int4 n4 = np[i];
            rows[1 + i * 4 + 0] = b * NN + n4.x;
            rows[1 + i * 4 + 1] = b * NN + n4.y;
            rows[1 + i * 4 + 2] = b * NN + n4.z;
            rows[1 + i * 4 + 3] = b * NN + n4.w;
        }
    }

    // Pass 1: scores (lane's head = ln16>>2). Unguarded loads.
    float sc[SS];
    #pragma unroll
    for (int s = 0; s < SS; ++s) {
        bf8 k8 = *(const bf8*)(Kh + (size_t)rows[s] * DD + ln16 * 8);
        float p = 0.f;
        #pragma unroll
        for (int i = 0; i < 8; ++i) p = fmaf(qf[i], bf2f_s(k8[i]), p);
        p += __shfl_xor(p, 1, 4);
        p += __shfl_xor(p, 2, 4);
        sc[s] = p * 0.17677669529663687f;   // 1/sqrt(32)
    }

    // Masked softmax over s in [0, len], redundantly per lane.
    const int len = vlen[v];
    float m = sc[0];
    #pragma unroll
    for (int s = 1; s < SS; ++s) m = (s <= len) ? fmaxf(m, sc[s]) : m;
    float sum = 0.f;
    #pragma unroll
    for (int s = 0; s < SS; ++s) {
        float e = (s <= len) ? __expf(sc[s] - m) : 0.f;
        sc[s] = e;
        sum += e;
    }
    const float inv = 1.f / sum;

    // Pass 2: weighted V accumulate
    float acc[8] = {};
    #pragma unroll
    for (int s = 0; s < SS; ++s) {
        bf8 v8 = *(const bf8*)(Vh + (size_t)rows[s] * DD + ln16 * 8);
        float w = sc[s] * inv;
        #pragma unroll
        for (int i = 0; i < 8; ++i) acc[i] = fmaf(w, bf2f_s(v8[i]), acc[i]);
    }

    // ctx -> LDS (bf16): row vloc, dims ln16*8..+8 == (H,DK) flat == Wo input
    {
        bf8 r;
        #pragma unroll
        for (int i = 0; i < 8; ++i) r[i] = (short)f2bf(acc[i]);
        *(bf8*)(Ct + vloc * WPAD + ln16 * 8) = r;
    }
    __syncthreads();    // Ct complete

    // ---------------- Wo -> relu(W1) -> W2, B-frags straight from L2 ------
    const int lane = tid & 63, wv = tid >> 6;   // wave wv owns cols wv*32..+31
    const int ln = lane & 15, quad = lane >> 4;
    const float* biases[3] = { bo, b1, b2 };

    #pragma unroll 1
    for (int g = 0; g < 3; ++g) {
        // A-frags: the 16 ctx rows (same for all 4 waves)
        bf8 afr[4];
        #pragma unroll
        for (int s = 0; s < 4; ++s)
            afr[s] = *(const bf8*)(Ct + ln * WPAD + s * 32 + quad * 8);

        // B-frags direct from global (L2-hot, 16B loads, zero staging)
        const unsigned short* Wg = WtT3 + g * 16384;
        bf8 bfr[2][4];
        #pragma unroll
        for (int t = 0; t < 2; ++t)
            #pragma unroll
            for (int s = 0; s < 4; ++s)
                bfr[t][s] = *(const bf8*)(Wg + (size_t)(wv * 32 + t * 16 + ln) * 128
                                             + s * 32 + quad * 8);

        f4 facc[2] = {};
        #pragma unroll
        for (int t = 0; t < 2; ++t)
            #pragma unroll
            for (int s = 0; s < 4; ++s)
                facc[t] = __builtin_amdgcn_mfma_f32_16x16x32_bf16(afr[s], bfr[t][s], facc[t], 0, 0, 0);

        const float* bias = biases[g];
        if (g == 2) {
            #pragma unroll
            for (int t = 0; t < 2; ++t) {
                int col = wv * 32 + t * 16 + ln;
                float bc = bias[col];
                #pragma unroll
                for (int r = 0; r < 4; ++r)
                    Out[(size_t)(row0 + quad * 4 + r) * DD + col] = facc[t][r] + bc;
            }
        } else {
            __syncthreads();   // all waves done reading Ct (afr) for this g
            #pragma unroll
            for (int t = 0; t < 2; ++t) {
                int col = wv * 32 + t * 16 + ln;
                float bc = bias[col];
                #pragma unroll
                for (int r = 0; r < 4; ++r) {
                    float vv = facc[t][r] + bc;
                    if (g == 1) vv = fmaxf(vv, 0.f);
                    Ct[(quad * 4 + r) * WPAD + col] = f2bf(vv);
                }
            }
            __syncthreads();   // new Ct visible before next g's afr reads
        }
    }
}

// ---------------------------------------------------------------------------
extern "C" void kernel_launch(void* const* d_in, const int* in_sizes, int n_in,
                              void* d_out, int out_size, void* d_ws, size_t ws_size,
                              hipStream_t stream)
{
    const float* vf   = (const float*)d_in[0];
    const int*   nbr  = (const int*)  d_in[1];
    const int*   vlen = (const int*)  d_in[2];
    const float* Wq   = (const float*)d_in[3];
    const float* bq   = (const float*)d_in[4];
    const float* Wk   = (const float*)d_in[5];
    const float* bk   = (const float*)d_in[6];
    const float* Wv   = (const float*)d_in[7];
    const float* bv   = (const float*)d_in[8];
    const float* Wo   = (const float*)d_in[9];
    const float* bo   = (const float*)d_in[10];
    const float* W1   = (const float*)d_in[11];
    const float* b1   = (const float*)d_in[12];
    const float* W2   = (const float*)d_in[13];
    const float* b2   = (const float*)d_in[14];

    float* out = (float*)d_out;

    const size_t SZ = (size_t)M_TOT * DD;
    unsigned short* WtT = (unsigned short*)d_ws;    // 6 x 16384 bf16
    unsigned short* qh  = WtT + 6 * 16384;
    unsigned short* kh  = qh + SZ;
    unsigned short* vh  = kh + SZ;

    cvt_wT<<<96, 256, 0, stream>>>(Wq, Wk, Wv, Wo, W1, W2, WtT);

    qkv_kernel<<<M_TOT / 64, 256, 0, stream>>>(vf, WtT, bq, bk, bv, qh, kh, vh);

    attn_ffn_kernel<<<M_TOT / 16, 256, 0, stream>>>(qh, kh, vh, nbr, vlen,
                                                    WtT + 3 * 16384, bo, b1, b2, out);
}

// Round 4
// 136.013 us; speedup vs baseline: 1.0764x; 1.0567x over previous
//
#include <hip/hip_runtime.h>
#include <math.h>

#define BB 4
#define NN 8192
#define KNB 16
#define DD 128
#define SS 17            // K+1 (self + neighbors)
#define M_TOT (BB*NN)    // 32768
#define WPAD 136         // padded inner stride (elems) for LDS tiles

typedef __attribute__((ext_vector_type(8))) short          bf8;
typedef __attribute__((ext_vector_type(4))) float          f4;
typedef __attribute__((ext_vector_type(4))) unsigned short u16x4;

static __device__ __forceinline__ unsigned short f2bf(float f) {
    unsigned u = __builtin_bit_cast(unsigned, f);
    u += 0x7fffu + ((u >> 16) & 1u);        // round-to-nearest-even
    return (unsigned short)(u >> 16);
}
static __device__ __forceinline__ float bf2f_s(short h) {
    return __builtin_bit_cast(float, (unsigned)(unsigned short)h << 16);
}

// ---------------------------------------------------------------------------
// Transpose+convert the six 128x128 fp32 weights to bf16 W^T[n][k].
// ---------------------------------------------------------------------------
__global__ __launch_bounds__(256) void cvt_wT(
    const float* __restrict__ Wq, const float* __restrict__ Wk,
    const float* __restrict__ Wv, const float* __restrict__ Wo,
    const float* __restrict__ W1, const float* __restrict__ W2,
    unsigned short* __restrict__ out)
{
    int m = blockIdx.x >> 4;
    const float* src = (m == 0) ? Wq : (m == 1) ? Wk : (m == 2) ? Wv
                     : (m == 3) ? Wo : (m == 4) ? W1 : W2;
    unsigned short* dst = out + m * 16384;
    int o = (blockIdx.x & 15) * 1024 + threadIdx.x * 4;   // output idx [n][k]
    int n = o >> 7, k = o & 127;
    u16x4 r;
    #pragma unroll
    for (int i = 0; i < 4; ++i) r[i] = f2bf(src[(size_t)(k + i) * 128 + n]);
    *(u16x4*)(dst + o) = r;
}

// ---------------------------------------------------------------------------
// Fused fp32->bf16 convert + QKV projection (round-0 proven structure).
// 64 rows/block, 4 waves; X staged ONCE, afr persistent across 3 GEMMs.
// K and V outputs are INTERLEAVED per row: kv[row][0:128]=K, [128:256]=V —
// the attn gather then needs ONE base address per row (V at +256 B imm).
// Fragment maps (m89-verified): A[m=lane&15][k=quad*8+j],
// B[k=quad*8+j][n=lane&15], D[row=quad*4+r][col=lane&15].
// LDS 17.4 + 34.8 = 52.2 KB -> 3 blocks/CU.
// ---------------------------------------------------------------------------
__global__ __launch_bounds__(256) void qkv_kernel(
    const float* __restrict__ X, const unsigned short* __restrict__ WtT,
    const float* __restrict__ bq, const float* __restrict__ bk,
    const float* __restrict__ bv,
    unsigned short* __restrict__ qh, unsigned short* __restrict__ kv)
{
    __shared__ unsigned short Xs[64 * WPAD];    // 17408 B
    __shared__ unsigned short Wb[128 * WPAD];   // 34816 B

    const int tid  = threadIdx.x;
    const int row0 = blockIdx.x * 64;

    // Stage X tile fp32 -> bf16 (coalesced float4 reads)
    {
        const float4* Xg = (const float4*)(X + (size_t)row0 * DD);
        #pragma unroll
        for (int i = 0; i < 8; ++i) {
            int idx = tid + i * 256;            // 0..2047
            int r = idx >> 5, c4 = idx & 31;
            float4 v = Xg[idx];
            u16x4 u;
            u[0] = f2bf(v.x); u[1] = f2bf(v.y); u[2] = f2bf(v.z); u[3] = f2bf(v.w);
            *(u16x4*)(Xs + r * WPAD + c4 * 4) = u;
        }
    }
    // Stage Wq^T
    #pragma unroll
    for (int i = 0; i < 8; ++i) {
        int c = tid + i * 256;
        int n = c >> 4, k8 = c & 15;
        *(bf8*)(Wb + n * WPAD + k8 * 8) = ((const bf8*)WtT)[c];
    }

    const int lane = tid & 63, wv = tid >> 6;   // wave owns rows wv*16..+15
    const int ln = lane & 15, quad = lane >> 4;
    __syncthreads();

    // A-frags: persistent across the 3 GEMMs (4 k-steps, 16 regs)
    bf8 afr[4];
    #pragma unroll
    for (int s = 0; s < 4; ++s)
        afr[s] = *(const bf8*)(Xs + (wv * 16 + ln) * WPAD + s * 32 + quad * 8);

    const float* biases[3] = { bq, bk, bv };
    unsigned short* outs[3] = { qh, kv, kv + 128 };
    const int strides[3] = { 128, 256, 256 };

    #pragma unroll 1
    for (int g = 0; g < 3; ++g) {
        if (g > 0) {
            __syncthreads();   // all waves done reading Wb for g-1
            const bf8* Wn = (const bf8*)(WtT + g * 16384);
            #pragma unroll
            for (int i = 0; i < 8; ++i) {
                int c = tid + i * 256;
                int n = c >> 4, k8 = c & 15;
                *(bf8*)(Wb + n * WPAD + k8 * 8) = Wn[c];
            }
            __syncthreads();
        }

        f4 acc[8] = {};
        #pragma unroll
        for (int t = 0; t < 8; ++t) {
            bf8 bfr[4];
            #pragma unroll
            for (int s = 0; s < 4; ++s)
                bfr[s] = *(const bf8*)(Wb + (t * 16 + ln) * WPAD + s * 32 + quad * 8);
            #pragma unroll
            for (int s = 0; s < 4; ++s)
                acc[t] = __builtin_amdgcn_mfma_f32_16x16x32_bf16(afr[s], bfr[s], acc[t], 0, 0, 0);
        }

        const float* bias = biases[g];
        unsigned short* Y = outs[g];
        const int st = strides[g];
        #pragma unroll
        for (int t = 0; t < 8; ++t) {
            int col = t * 16 + ln;
            float bc = bias[col];
            #pragma unroll
            for (int r = 0; r < 4; ++r) {
                int row = row0 + wv * 16 + quad * 4 + r;
                Y[(size_t)row * st + col] = f2bf(acc[t][r] + bc);
            }
        }
    }
}

// ---------------------------------------------------------------------------
// Attention, register-resident, S-SPLIT. 32 lanes per vertex: ln16 owns 8
// dims (as round 0), sp in {0,1} owns half the 17 rows (9 + 8). Per-lane
// dependent loads halve (34 -> 18) and live state halves (rows[9]+sc[9])
// -> lower VGPR + shorter latency chain. Cross-half combine: shfl_xor(16).
// 8 vertices/block, 4096 blocks. Loads unguarded (round-1 lesson); sp1's
// dummy slot s=17 points at row v and gets arithmetic weight 0.
// XCD swizzle: batch b pinned to XCD pair {2b,2b+1}.
// ---------------------------------------------------------------------------
__global__ __launch_bounds__(256) void attn_kernel(
    const unsigned short* __restrict__ Qh, const unsigned short* __restrict__ KV,
    const int* __restrict__ nbr, const int* __restrict__ vlen,
    unsigned short* __restrict__ Ctx)
{
    const int tid  = threadIdx.x;
    const int vloc = tid >> 5;        // 0..7
    const int sp   = (tid >> 4) & 1;  // s-half
    const int ln16 = tid & 15;        // 8-dim slot
    const int blk  = blockIdx.x;
    const int b    = (blk & 7) >> 1;                 // batch from XCD pair
    const int j    = ((blk >> 3) << 1) | (blk & 1);  // within-batch group 0..1023
    const int v    = b * NN + j * 8 + vloc;
    const int len  = vlen[v];         // rows 0..len valid (len in [0,16))

    // q fragment: 8 dims (lane's head = ln16>>2)
    bf8 q8 = *(const bf8*)(Qh + (size_t)v * DD + ln16 * 8);
    float qf[8];
    #pragma unroll
    for (int i = 0; i < 8; ++i) qf[i] = bf2f_s(q8[i]);

    // This half's 9 rows. sp0: {self, nbr0..7} (s=0..8); sp1: {nbr8..15, self-dummy}
    int rows[9];
    {
        const int4* np = (const int4*)(nbr + (size_t)v * KNB);
        if (sp == 0) {
            rows[0] = v;
            int4 a = np[0], c = np[1];
            rows[1] = b * NN + a.x; rows[2] = b * NN + a.y;
            rows[3] = b * NN + a.z; rows[4] = b * NN + a.w;
            rows[5] = b * NN + c.x; rows[6] = b * NN + c.y;
            rows[7] = b * NN + c.z; rows[8] = b * NN + c.w;
        } else {
            int4 a = np[2], c = np[3];
            rows[0] = b * NN + a.x; rows[1] = b * NN + a.y;
            rows[2] = b * NN + a.z; rows[3] = b * NN + a.w;
            rows[4] = b * NN + c.x; rows[5] = b * NN + c.y;
            rows[6] = b * NN + c.z; rows[7] = b * NN + c.w;
            rows[8] = v;            // dummy: s=17 > len always -> weight 0
        }
    }
    const int s0 = sp * 9;

    // Pass 1: scores for this half's rows. Unguarded loads, arithmetic mask.
    float sc[9];
    #pragma unroll
    for (int i = 0; i < 9; ++i) {
        bf8 k8 = *(const bf8*)(KV + (size_t)rows[i] * 256 + ln16 * 8);
        float p = 0.f;
        #pragma unroll
        for (int d = 0; d < 8; ++d) p = fmaf(qf[d], bf2f_s(k8[d]), p);
        p += __shfl_xor(p, 1, 4);
        p += __shfl_xor(p, 2, 4);
        sc[i] = (s0 + i <= len) ? p * 0.17677669529663687f : -1.0e9f;  // 1/sqrt(32)
    }

    // Softmax across both halves: max/sum via shfl_xor(16).
    float m = sc[0];
    #pragma unroll
    for (int i = 1; i < 9; ++i) m = fmaxf(m, sc[i]);
    m = fmaxf(m, __shfl_xor(m, 16));
    float sum = 0.f;
    #pragma unroll
    for (int i = 0; i < 9; ++i) {
        float e = __expf(sc[i] - m);    // invalid: exp(-1e9 - m) == 0
        sc[i] = e;
        sum += e;
    }
    sum += __shfl_xor(sum, 16);
    const float inv = 1.f / sum;

    // Pass 2: weighted V accumulate for this half (V at +128 elems = imm offset)
    float acc[8] = {};
    #pragma unroll
    for (int i = 0; i < 9; ++i) {
        bf8 v8 = *(const bf8*)(KV + (size_t)rows[i] * 256 + 128 + ln16 * 8);
        float w = sc[i] * inv;
        #pragma unroll
        for (int d = 0; d < 8; ++d) acc[d] = fmaf(w, bf2f_s(v8[d]), acc[d]);
    }
    // combine halves
    #pragma unroll
    for (int d = 0; d < 8; ++d) acc[d] += __shfl_xor(acc[d], 16);

    if (sp == 0) {
        bf8 r;
        #pragma unroll
        for (int d = 0; d < 8; ++d) r[d] = (short)f2bf(acc[d]);
        *(bf8*)(Ctx + (size_t)v * DD + ln16 * 8) = r;
    }
}

// ---------------------------------------------------------------------------
// Fused Wo + FFN(W1,relu,W2): ctx -> out, chained through one LDS tile.
// 64 rows/block, 4 waves, wave tile 16x128. LDS 52.2 KB -> 3 blocks/CU.
// (round-0 proven version, unchanged)
// ---------------------------------------------------------------------------
__global__ __launch_bounds__(256) void ffn_kernel(
    const unsigned short* __restrict__ Ctxg, const unsigned short* __restrict__ WtT3,
    const float* __restrict__ bo, const float* __restrict__ b1,
    const float* __restrict__ b2, float* __restrict__ Out)
{
    __shared__ unsigned short Ct[64 * WPAD];
    __shared__ unsigned short Wb[128 * WPAD];

    const int tid  = threadIdx.x;
    const int row0 = blockIdx.x * 64;

    {
        const bf8* Cg = (const bf8*)(Ctxg + (size_t)row0 * DD);
        #pragma unroll
        for (int i = 0; i < 4; ++i) {
            int idx = tid + i * 256;
            int r = idx >> 4, c8 = idx & 15;
            *(bf8*)(Ct + r * WPAD + c8 * 8) = Cg[idx];
        }
    }
    #pragma unroll
    for (int i = 0; i < 8; ++i) {
        int c = tid + i * 256;
        int n = c >> 4, k8 = c & 15;
        *(bf8*)(Wb + n * WPAD + k8 * 8) = ((const bf8*)WtT3)[c];
    }

    const int lane = tid & 63, wv = tid >> 6;
    const int ln = lane & 15, quad = lane >> 4;
    const float* biases[3] = { bo, b1, b2 };
    __syncthreads();

    #pragma unroll 1
    for (int g = 0; g < 3; ++g) {
        bf8 afr[4];
        #pragma unroll
        for (int s = 0; s < 4; ++s)
            afr[s] = *(const bf8*)(Ct + (wv * 16 + ln) * WPAD + s * 32 + quad * 8);

        f4 acc[8] = {};
        #pragma unroll
        for (int t = 0; t < 8; ++t) {
            bf8 bfr[4];
            #pragma unroll
            for (int s = 0; s < 4; ++s)
                bfr[s] = *(const bf8*)(Wb + (t * 16 + ln) * WPAD + s * 32 + quad * 8);
            #pragma unroll
            for (int s = 0; s < 4; ++s)
                acc[t] = __builtin_amdgcn_mfma_f32_16x16x32_bf16(afr[s], bfr[s], acc[t], 0, 0, 0);
        }

        __syncthreads();   // everyone done reading Ct & Wb

        const float* bias = biases[g];
        if (g == 2) {
            #pragma unroll
            for (int t = 0; t < 8; ++t) {
                int col = t * 16 + ln;
                float bc = bias[col];
                #pragma unroll
                for (int r = 0; r < 4; ++r) {
                    int row = row0 + wv * 16 + quad * 4 + r;
                    Out[(size_t)row * DD + col] = acc[t][r] + bc;
                }
            }
        } else {
            const bf8* Wn = (const bf8*)(WtT3 + (g + 1) * 16384);
            #pragma unroll
            for (int i = 0; i < 8; ++i) {
                int c = tid + i * 256;
                int n = c >> 4, k8 = c & 15;
                *(bf8*)(Wb + n * WPAD + k8 * 8) = Wn[c];
            }
            #pragma unroll
            for (int t = 0; t < 8; ++t) {
                int col = t * 16 + ln;
                float bc = bias[col];
                #pragma unroll
                for (int r = 0; r < 4; ++r) {
                    int rloc = wv * 16 + quad * 4 + r;
                    float vv = acc[t][r] + bc;
                    if (g == 1) vv = fmaxf(vv, 0.f);
                    Ct[rloc * WPAD + col] = f2bf(vv);
                }
            }
            __syncthreads();
        }
    }
}

// ---------------------------------------------------------------------------
extern "C" void kernel_launch(void* const* d_in, const int* in_sizes, int n_in,
                              void* d_out, int out_size, void* d_ws, size_t ws_size,
                              hipStream_t stream)
{
    const float* vf   = (const float*)d_in[0];
    const int*   nbr  = (const int*)  d_in[1];
    const int*   vlen = (const int*)  d_in[2];
    const float* Wq   = (const float*)d_in[3];
    const float* bq   = (const float*)d_in[4];
    const float* Wk   = (const float*)d_in[5];
    const float* bk   = (const float*)d_in[6];
    const float* Wv   = (const float*)d_in[7];
    const float* bv   = (const float*)d_in[8];
    const float* Wo   = (const float*)d_in[9];
    const float* bo   = (const float*)d_in[10];
    const float* W1   = (const float*)d_in[11];
    const float* b1   = (const float*)d_in[12];
    const float* W2   = (const float*)d_in[13];
    const float* b2   = (const float*)d_in[14];

    float* out = (float*)d_out;

    const size_t SZ = (size_t)M_TOT * DD;
    unsigned short* WtT = (unsigned short*)d_ws;    // 6 x 16384 bf16
    unsigned short* qh  = WtT + 6 * 16384;
    unsigned short* kv  = qh + SZ;                  // interleaved K|V, 2*SZ
    unsigned short* ctx = kv + 2 * SZ;

    cvt_wT<<<96, 256, 0, stream>>>(Wq, Wk, Wv, Wo, W1, W2, WtT);

    qkv_kernel<<<M_TOT / 64, 256, 0, stream>>>(vf, WtT, bq, bk, bv, qh, kv);

    attn_kernel<<<M_TOT / 8, 256, 0, stream>>>(qh, kv, nbr, vlen, ctx);

    ffn_kernel<<<M_TOT / 64, 256, 0, stream>>>(ctx, WtT + 3 * 16384, bo, b1, b2, out);
}